// Round 1
// 3909.373 us; speedup vs baseline: 1.0881x; 1.0881x over previous
//
#include <hip/hip_runtime.h>
#include <cmath>

#define Tn 512
#define Bn 32
#define Hn 1024

typedef short bf16x8 __attribute__((ext_vector_type(8)));
typedef float f32x4 __attribute__((ext_vector_type(4)));

__device__ __forceinline__ unsigned short f2bf_rne(float f) {
    unsigned u = __float_as_uint(f);
    unsigned r = (u + 0x7fffu + ((u >> 16) & 1u)) >> 16;
    return (unsigned short)r;
}
__device__ __forceinline__ float bf2f(unsigned short h) {
    return __uint_as_float((unsigned)h << 16);
}
__device__ __forceinline__ bf16x8 cvt8(float4 a, float4 b) {
    union { unsigned u[4]; bf16x8 v; } o;
    o.u[0] = (unsigned)f2bf_rne(a.x) | ((unsigned)f2bf_rne(a.y) << 16);
    o.u[1] = (unsigned)f2bf_rne(a.z) | ((unsigned)f2bf_rne(a.w) << 16);
    o.u[2] = (unsigned)f2bf_rne(b.x) | ((unsigned)f2bf_rne(b.y) << 16);
    o.u[3] = (unsigned)f2bf_rne(b.z) | ((unsigned)f2bf_rne(b.w) << 16);
    return o.v;
}
__device__ __forceinline__ bf16x8 as_bf8(uint4 u) {
    union { uint4 q; bf16x8 v; } o; o.q = u; return o.v;
}

// fast activations: v_exp + v_rcp approx (err ~1e-6 << bf16-h quantum 2^-9)
__device__ __forceinline__ float fsigf(float x) {
    return __builtin_amdgcn_rcpf(1.f + __expf(-x));
}
__device__ __forceinline__ float ftanhf(float x) {
    return 1.f - 2.f * __builtin_amdgcn_rcpf(1.f + __expf(2.f * x));
}

// ---- explicitly coherent (LLC point-of-coherence) access helpers ----------
__device__ __forceinline__ void gstore_u32_sc(unsigned* p, unsigned v) {
    asm volatile("global_store_dword %0, %1, off sc0 sc1\n\t"
                 "s_waitcnt vmcnt(0)"
                 :: "v"(p), "v"(v) : "memory");
}
__device__ __forceinline__ void gstore_u32_nd(unsigned* p, unsigned v) {
    // no self-drain: caller drains wave-wide once after all lanes' stores
    asm volatile("global_store_dword %0, %1, off sc0 sc1"
                 :: "v"(p), "v"(v) : "memory");
}
__device__ __forceinline__ unsigned gload_u32_sc(const unsigned* p) {
    unsigned r;
    asm volatile("global_load_dword %0, %1, off sc0 sc1\n\t"
                 "s_waitcnt vmcnt(0)"
                 : "=&v"(r) : "v"(p) : "memory");
    return r;
}
__device__ __forceinline__ void gload_h_sc(const unsigned short* b0,
                                           const unsigned short* b1,
                                           uint4* o0, uint4* o1) {
    asm volatile(
        "global_load_dwordx4 %0, %8, off sc0 sc1\n\t"
        "global_load_dwordx4 %1, %8, off offset:64 sc0 sc1\n\t"
        "global_load_dwordx4 %2, %8, off offset:128 sc0 sc1\n\t"
        "global_load_dwordx4 %3, %8, off offset:192 sc0 sc1\n\t"
        "global_load_dwordx4 %4, %9, off sc0 sc1\n\t"
        "global_load_dwordx4 %5, %9, off offset:64 sc0 sc1\n\t"
        "global_load_dwordx4 %6, %9, off offset:128 sc0 sc1\n\t"
        "global_load_dwordx4 %7, %9, off offset:192 sc0 sc1\n\t"
        "s_waitcnt vmcnt(0)"
        : "=&v"(o0[0]), "=&v"(o0[1]), "=&v"(o0[2]), "=&v"(o0[3]),
          "=&v"(o1[0]), "=&v"(o1[1]), "=&v"(o1[2]), "=&v"(o1[3])
        : "v"(b0), "v"(b1)
        : "memory");
}

__global__ void lstm_flags_init(unsigned* flags) { flags[threadIdx.x] = 0u; }

// ---------------------------------------------------------------------------
// Persistent bf16-MFMA LSTM, single-barrier step pipeline.
//   - per-wave producer-subset poll: wave wv gates on blocks [32wv,32wv+32)
//     (its k-slice producers) + own-block flag (orders lds_r reuse; replaces
//     the post-poll __syncthreads).
//   - fused stage2-reduce + activations + h-store in 16 lanes of EVERY wave;
//     each wave drains its own stores (vmcnt is per-wave), then LDS atomicAdd;
//     8th arriver publishes the block flag. Barriers (c),(d) removed; the
//     16-way-bank-conflict reduce pattern removed.
//   - hi/lo MFMA accumulators split into 4 independent chains.
// ---------------------------------------------------------------------------
__global__ __launch_bounds__(512, 2) void lstm_persist_mfma(
    const float* __restrict__ x,       // [B,T,H] fp32
    const float* __restrict__ w_ih,    // [4H,H] fp32
    const float* __restrict__ w_hh,    // [4H,H] fp32
    const float* __restrict__ b_ih,    // [4H]
    const float* __restrict__ b_hh,    // [4H]
    unsigned short* __restrict__ hbuf, // ws: 2 x [32][1024] bf16
    unsigned* __restrict__ flags,      // ws: [256] u32, zeroed
    float* __restrict__ out)           // [B,H] fp32
{
    extern __shared__ char smem[];
    unsigned short* lds_w = (unsigned short*)smem;            // 32 x 2056 bf16
    float* lds_r = (float*)(smem + 131584);                   // 16 x 256 f32
    unsigned* lds_cnt = (unsigned*)(smem + 131584 + 16384);   // 1 u32

    const int tid = threadIdx.x;
    const int bj  = blockIdx.x;
    const int wv  = tid >> 6;          // 0..7  k-slice
    const int ln  = tid & 63;
    const int l15 = ln & 15;
    const int qd  = ln >> 4;           // 0..3

    if (tid == 0) *lds_cnt = 0u;

    // ---- stage W (hi+lo split bf16) into LDS, once ----
    for (int i = 0; i < 16; ++i) {
        int slot = i * 512 + tid;
        int r    = slot >> 9;
        int f4   = slot & 511;
        int n    = (r >> 2) * Hn + bj * 4 + (r & 3);
        float4 v = (f4 < 256) ? ((const float4*)(w_ih + (size_t)n * Hn))[f4]
                              : ((const float4*)(w_hh + (size_t)n * Hn))[f4 - 256];
        unsigned short h0 = f2bf_rne(v.x), h1 = f2bf_rne(v.y);
        unsigned short h2 = f2bf_rne(v.z), h3 = f2bf_rne(v.w);
        unsigned short l0 = f2bf_rne(v.x - bf2f(h0)), l1 = f2bf_rne(v.y - bf2f(h1));
        unsigned short l2 = f2bf_rne(v.z - bf2f(h2)), l3 = f2bf_rne(v.w - bf2f(h3));
        uint2 ph, pl;
        ph.x = (unsigned)h0 | ((unsigned)h1 << 16);
        ph.y = (unsigned)h2 | ((unsigned)h3 << 16);
        pl.x = (unsigned)l0 | ((unsigned)l1 << 16);
        pl.y = (unsigned)l2 | ((unsigned)l3 << 16);
        *(uint2*)(lds_w + (size_t)r        * 2056 + f4 * 4) = ph;
        *(uint2*)(lds_w + (size_t)(r + 16) * 2056 + f4 * 4) = pl;
    }

    // finalize lanes: ln<16 of EVERY wave; element e = wv*16+ln
    //   b = e>>2 (batch), cl = e&3 (col within block's 4)
    float bias0 = 0.f, bias1 = 0.f, bias2 = 0.f, bias3 = 0.f, creg = 0.f;
    if (ln < 16) {
        int col = bj * 4 + (ln & 3);
        bias0 = b_ih[col]          + b_hh[col];
        bias1 = b_ih[Hn + col]     + b_hh[Hn + col];
        bias2 = b_ih[2 * Hn + col] + b_hh[2 * Hn + col];
        bias3 = b_ih[3 * Hn + col] + b_hh[3 * Hn + col];
    }
    __syncthreads();

    const unsigned short* whi_base = lds_w + (size_t)l15 * 2056 + qd * 8;
    const unsigned short* wlo_base = lds_w + (size_t)(l15 + 16) * 2056 + qd * 8;
    const float* xr0 = x + (size_t)l15        * (Tn * Hn) + wv * 128 + qd * 8;
    const float* xr1 = x + (size_t)(16 + l15) * (Tn * Hn) + wv * 128 + qd * 8;
    const size_t hoff0 = (size_t)l15        * Hn + wv * 128 + qd * 8;
    const size_t hoff1 = (size_t)(16 + l15) * Hn + wv * 128 + qd * 8;

    // ---- preload x fragments for t=0 ----
    float4 xa0[4], xb0[4], xa1[4], xb1[4];
    #pragma unroll
    for (int j = 0; j < 4; ++j) {
        xa0[j] = *(const float4*)(xr0 + j * 32);
        xb0[j] = *(const float4*)(xr0 + j * 32 + 4);
        xa1[j] = *(const float4*)(xr1 + j * 32);
        xb1[j] = *(const float4*)(xr1 + j * 32 + 4);
    }

    for (int t = 0; t < Tn; ++t) {
        // 4 independent accumulator chains (hi/lo x batch-half)
        f32x4 a0h = {0.f,0.f,0.f,0.f}, a0l = {0.f,0.f,0.f,0.f};
        f32x4 a1h = {0.f,0.f,0.f,0.f}, a1l = {0.f,0.f,0.f,0.f};

        // ---- issue x prefetch for t+1 ----
        float4 na0[4], nb0[4], na1[4], nb1[4];
        {
            const int tn = (t + 1 < Tn) ? (t + 1) : t;
            const float* p0 = xr0 + (size_t)tn * Hn;
            const float* p1 = xr1 + (size_t)tn * Hn;
            #pragma unroll
            for (int j = 0; j < 4; ++j) {
                na0[j] = *(const float4*)(p0 + j * 32);
                nb0[j] = *(const float4*)(p0 + j * 32 + 4);
                na1[j] = *(const float4*)(p1 + j * 32);
                nb1[j] = *(const float4*)(p1 + j * 32 + 4);
            }
        }

        // ---- x-phase MFMAs ----
        #pragma unroll
        for (int j = 0; j < 4; ++j) {
            const int koff = wv * 128 + j * 32;
            bf16x8 ahi = *(const bf16x8*)(whi_base + koff);
            bf16x8 alo = *(const bf16x8*)(wlo_base + koff);
            bf16x8 bf0 = cvt8(xa0[j], xb0[j]);
            bf16x8 bf1 = cvt8(xa1[j], xb1[j]);
            a0h = __builtin_amdgcn_mfma_f32_16x16x32_bf16(ahi, bf0, a0h, 0, 0, 0);
            a0l = __builtin_amdgcn_mfma_f32_16x16x32_bf16(alo, bf0, a0l, 0, 0, 0);
            a1h = __builtin_amdgcn_mfma_f32_16x16x32_bf16(ahi, bf1, a1h, 0, 0, 0);
            a1l = __builtin_amdgcn_mfma_f32_16x16x32_bf16(alo, bf1, a1l, 0, 0, 0);
        }

        // ---- per-wave producer-subset poll + h-phase ----
        if (t > 0) {
            {
                // lanes 0..31: producer blocks of this wave's k-slice;
                // lanes 32..63: own-block flag (orders lds_r overwrite vs
                // previous step's fused finalize across all waves).
                const int src = (ln < 32) ? (wv * 32 + ln) : bj;
                const unsigned* fp = flags + src;
                bool done = false;
                for (;;) {
                    if (!done) done = (gload_u32_sc(fp) >= (unsigned)t);
                    if (__all((int)done)) break;
                }
            }
            const unsigned short* hb = hbuf + (size_t)((t - 1) & 1) * (Bn * Hn);
            uint4 hf0[4], hf1[4];
            gload_h_sc(hb + hoff0, hb + hoff1, hf0, hf1);
            #pragma unroll
            for (int j = 0; j < 4; ++j) {
                const int koff = 1024 + wv * 128 + j * 32;
                bf16x8 ahi = *(const bf16x8*)(whi_base + koff);
                bf16x8 alo = *(const bf16x8*)(wlo_base + koff);
                bf16x8 bf0 = as_bf8(hf0[j]);
                bf16x8 bf1 = as_bf8(hf1[j]);
                a0h = __builtin_amdgcn_mfma_f32_16x16x32_bf16(ahi, bf0, a0h, 0, 0, 0);
                a0l = __builtin_amdgcn_mfma_f32_16x16x32_bf16(alo, bf0, a0l, 0, 0, 0);
                a1h = __builtin_amdgcn_mfma_f32_16x16x32_bf16(ahi, bf1, a1h, 0, 0, 0);
                a1l = __builtin_amdgcn_mfma_f32_16x16x32_bf16(alo, bf1, a1l, 0, 0, 0);
            }
        }

        // ---- cross-wave k-reduction: write partials ----
        {
            f32x4 acc0 = a0h + a0l;
            f32x4 acc1 = a1h + a1l;
            float* pr0 = lds_r + (wv * 2 + 0) * 256 + l15;
            float* pr1 = lds_r + (wv * 2 + 1) * 256 + l15;
            #pragma unroll
            for (int r = 0; r < 4; ++r) {
                pr0[(qd * 4 + r) * 16] = acc0[r];   // D row = qd*4+r, col = l15
                pr1[(qd * 4 + r) * 16] = acc1[r];
            }
        }
        __syncthreads();   // the ONLY block barrier per step

        // ---- fused stage2 reduce + activations + h publish (16 lanes/wave) ----
        if (ln < 16) {
            const int e   = (wv << 4) | ln;     // 0..127
            const int b   = e >> 2;             // batch 0..31
            const int cl  = e & 3;              // col within block
            const int bt  = b >> 4, c16 = b & 15;
            float s0 = 0.f, s1 = 0.f, s2 = 0.f, s3 = 0.f;
            #pragma unroll
            for (int w8 = 0; w8 < 8; ++w8) {
                const float* base = lds_r + (w8 * 2 + bt) * 256 + c16;
                s0 += base[(0 * 4 + cl) * 16];
                s1 += base[(1 * 4 + cl) * 16];
                s2 += base[(2 * 4 + cl) * 16];
                s3 += base[(3 * 4 + cl) * 16];
            }
            float iv = fsigf(s0 + bias0);
            float fv = fsigf(s1 + bias1);
            float gv = ftanhf(s2 + bias2);
            float ov = fsigf(s3 + bias3);
            creg = fv * creg + iv * gv;
            float hn = ov * ftanhf(creg);
            unsigned short hv = f2bf_rne(hn);
            unsigned up = (unsigned)__shfl_xor((int)(unsigned)hv, 1, 64);
            if (!(ln & 1)) {          // cl even: pack [cl, cl+1] into u32
                unsigned pack = (unsigned)hv | (up << 16);
                unsigned short* hw = hbuf + (size_t)(t & 1) * (Bn * Hn)
                                   + (size_t)b * Hn + bj * 4 + cl;
                gstore_u32_nd((unsigned*)hw, pack);
            }
            if (t == Tn - 1) out[(size_t)b * Hn + bj * 4 + cl] = hn;
        }
        // wave-wide drain of this wave's h stores (vmcnt is per-wave)
        asm volatile("s_waitcnt vmcnt(0)" ::: "memory");
        if (ln == 0) {
            unsigned old = atomicAdd(lds_cnt, 1u);
            // 8th wave of this step: all waves' stores are drained -> publish
            if (old == 8u * (unsigned)t + 7u && (t + 1 < Tn))
                gstore_u32_sc(&flags[bj], (unsigned)(t + 1));
        }

        // ---- rotate x prefetch regs ----
        #pragma unroll
        for (int j = 0; j < 4; ++j) {
            xa0[j] = na0[j]; xb0[j] = nb0[j];
            xa1[j] = na1[j]; xb1[j] = nb1[j];
        }
    }
}

// ---------------------------------------------------------------------------
extern "C" void kernel_launch(void* const* d_in, const int* in_sizes, int n_in,
                              void* d_out, int out_size, void* d_ws, size_t ws_size,
                              hipStream_t stream) {
    const float* x    = (const float*)d_in[0];
    const float* w_ih = (const float*)d_in[1];
    const float* w_hh = (const float*)d_in[2];
    const float* b_ih = (const float*)d_in[3];
    const float* b_hh = (const float*)d_in[4];
    float* out = (float*)d_out;

    char* ws = (char*)d_ws;
    unsigned*       flags = (unsigned*)ws;                      // 1 KB
    unsigned short* hbuf  = (unsigned short*)(ws + 1024);       // 2 x 64 KB bf16
    (void)in_sizes; (void)n_in; (void)out_size; (void)ws_size;

    const size_t smem_bytes = 131584 + 16384 + 16;              // 147984 B

    lstm_flags_init<<<dim3(1), dim3(256), 0, stream>>>(flags);
    lstm_persist_mfma<<<dim3(256), dim3(512), smem_bytes, stream>>>(
        x, w_ih, w_hh, b_ih, b_hh, hbuf, flags, out);
}